// Round 5
// baseline (29.897 us; speedup 1.0000x reference)
//
#include <hip/hip_runtime.h>

#define NBIN 50
#define DIM  64
#define TPB  256
#define KPT  4

typedef float f32x2 __attribute__((ext_vector_type(2)));

// t = v * s + c   (s wave-uniform -> SGPR pair; one scalar operand per VOP3P ok)
__device__ __forceinline__ f32x2 pk_fma_vs(f32x2 v, f32x2 s, f32x2 c) {
    f32x2 r;
    asm("v_pk_fma_f32 %0, %1, %2, %3" : "=v"(r) : "v"(v), "s"(s), "v"(c));
    return r;
}
// acc = s * t + acc
__device__ __forceinline__ f32x2 pk_fma_acc(f32x2 s, f32x2 t, f32x2 acc) {
    asm("v_pk_fma_f32 %0, %1, %2, %0" : "+v"(acc) : "s"(s), "v"(t));
    return acc;
}

// partner value from lane ^ J, cheapest pipe per J
template <int J>
__device__ __forceinline__ int xor_partner(int v) {
    if constexpr (J == 1)  return __builtin_amdgcn_mov_dpp(v, 0xB1, 0xF, 0xF, false); // quad_perm [1,0,3,2]
    else if constexpr (J == 2)  return __builtin_amdgcn_mov_dpp(v, 0x4E, 0xF, 0xF, false); // quad_perm [2,3,0,1]
    else if constexpr (J == 32) return __shfl_xor(v, 32, 64);                               // ds_bpermute
    else return __builtin_amdgcn_ds_swizzle(v, (J << 10) | 0x1F);                           // xor BitMode
}

template <int K, int J>
__device__ __forceinline__ void bstep(int& key, int lane) {
    int partner = xor_partner<J>(key);
    int mn = key < partner ? key : partner;
    int mx = key < partner ? partner : key;
    bool keep_small = ((lane & J) == 0) == ((lane & K) == 0);
    key = keep_small ? mn : mx;
}

__device__ __forceinline__ void sort64(int& k, int lane) {
    bstep<2, 1>(k, lane);
    bstep<4, 2>(k, lane);  bstep<4, 1>(k, lane);
    bstep<8, 4>(k, lane);  bstep<8, 2>(k, lane);  bstep<8, 1>(k, lane);
    bstep<16, 8>(k, lane); bstep<16, 4>(k, lane); bstep<16, 2>(k, lane); bstep<16, 1>(k, lane);
    bstep<32, 16>(k, lane); bstep<32, 8>(k, lane); bstep<32, 4>(k, lane); bstep<32, 2>(k, lane); bstep<32, 1>(k, lane);
    bstep<64, 32>(k, lane); bstep<64, 16>(k, lane); bstep<64, 8>(k, lane); bstep<64, 4>(k, lane); bstep<64, 2>(k, lane); bstep<64, 1>(k, lane);
}

__global__ __launch_bounds__(TPB, 6) void scorer_kernel(
    const float* __restrict__ goal,   // (B, K, 2)
    const float* __restrict__ ego,    // (B, 4)
    const float* __restrict__ W1,     // (56, 64) row-major
    const float* __restrict__ b1,     // (64)
    const float* __restrict__ W2,     // (64, 1)
    const float* __restrict__ b2,     // (1)
    float* __restrict__ out)          // (B, K), K = 1024
{
    __shared__ float4 comb[16 * NBIN];   // [d4][bin] float4, 12.8 KB

    const int b    = blockIdx.x;
    const int tid  = threadIdx.x;
    const int lane = tid & 63;

    // 4 points per thread, strided by 256 so per-batch loads/stores coalesce
    const float2* gp = (const float2*)goal + (size_t)b * (TPB * KPT);
    float2 p[KPT];
    int    bin[KPT];
#pragma unroll
    for (int j = 0; j < KPT; ++j) {
        p[j] = gp[j * TPB + tid];
        // exact IEEE f32 replication of jax: floor((sqrt(x*x+y*y)/50)*50), clipped
        float r2 = __fadd_rn(__fmul_rn(p[j].x, p[j].x), __fmul_rn(p[j].y, p[j].y));
        float fv = floorf(__fmul_rn(__fdiv_rn(__fsqrt_rn(r2), 50.0f), 50.0f));
        int ix = (int)fv;
        bin[j] = ix < 0 ? 0 : (ix > NBIN - 1 ? NBIN - 1 : ix);
    }

    // table: comb[bin][d] = W1[bin][d] + b1[d] + ego@W1[52:56]; this thread's
    // column d = tid & 63 is fixed (256 | 64), so fold ego once in a register
    const int   d  = tid & 63;
    const float4 eg = ((const float4*)ego)[b];
    const float ev = b1[d]
                   + eg.x * W1[52 * DIM + d]
                   + eg.y * W1[53 * DIM + d]
                   + eg.z * W1[54 * DIM + d]
                   + eg.w * W1[55 * DIM + d];
    for (int i = tid; i < NBIN * DIM; i += TPB) {
        int bn = i >> 6;
        ((float*)comb)[((d >> 2) * NBIN + bn) * 4 + (d & 3)] = W1[i] + ev;
    }
    __syncthreads();

    const f32x2* w50v = (const f32x2*)(W1 + 50 * DIM);
    const f32x2* w51v = (const f32x2*)(W1 + 51 * DIM);
    const f32x2* w2v  = (const f32x2*)W2;
    const float  bias2 = b2[0];

#pragma unroll
    for (int j = 0; j < KPT; ++j) {
        // in-wave sort by bin: key = bin<<6 | lane (unique)
        int key = (bin[j] << 6) | lane;
        sort64(key, lane);
        const int origin = key & 63;
        const int sbin   = key >> 6;
        const float xs = __shfl(p[j].x, origin, 64);   // ds_bpermute pull
        const float ys = __shfl(p[j].y, origin, 64);

        const f32x2 xx = {xs, xs}, yy = {ys, ys};
        f32x2 al = {0.f, 0.f}, ah = {0.f, 0.f};
#pragma unroll
        for (int d4 = 0; d4 < 16; ++d4) {
            const f32x2 wa0 = w50v[d4 * 2], wa1 = w50v[d4 * 2 + 1];
            const f32x2 wu0 = w51v[d4 * 2], wu1 = w51v[d4 * 2 + 1];
            const f32x2 wc0 = w2v[d4 * 2],  wc1 = w2v[d4 * 2 + 1];
            const float4 g = comb[d4 * NBIN + sbin];   // sorted -> conflict-free
            f32x2 t;
            t = pk_fma_vs(yy, wu0, (f32x2){g.x, g.y});
            t = pk_fma_vs(xx, wa0, t);
            t.x = fmaxf(t.x, 0.0f); t.y = fmaxf(t.y, 0.0f);
            al = pk_fma_acc(wc0, t, al);
            t = pk_fma_vs(yy, wu1, (f32x2){g.z, g.w});
            t = pk_fma_vs(xx, wa1, t);
            t.x = fmaxf(t.x, 0.0f); t.y = fmaxf(t.y, 0.0f);
            ah = pk_fma_acc(wc1, t, ah);
        }
        float s = al.x + al.y + ah.x + ah.y + bias2;

        // push score back to the lane that owns this k (ds_permute)
        int sb = __builtin_amdgcn_ds_permute(origin << 2, __float_as_int(s));
        out[(size_t)b * (TPB * KPT) + j * TPB + tid] = __int_as_float(sb);
    }
}

extern "C" void kernel_launch(void* const* d_in, const int* in_sizes, int n_in,
                              void* d_out, int out_size, void* d_ws, size_t ws_size,
                              hipStream_t stream) {
    const float* goal = (const float*)d_in[0];
    const float* ego  = (const float*)d_in[1];
    const float* W1   = (const float*)d_in[2];
    const float* b1   = (const float*)d_in[3];
    const float* W2   = (const float*)d_in[4];
    const float* b2   = (const float*)d_in[5];
    float* out = (float*)d_out;

    int B = in_sizes[1] / 4;          // ego_state is (B, 4); K fixed at 1024
    scorer_kernel<<<dim3(B), dim3(TPB), 0, stream>>>(goal, ego, W1, b1, W2, b2, out);
}

// Round 6
// 21.902 us; speedup vs baseline: 1.3650x; 1.3650x over previous
//
#include <hip/hip_runtime.h>

#define NBIN 50
#define DIM  64
#define TPB  256

typedef _Float16 h2 __attribute__((ext_vector_type(2)));

__device__ __forceinline__ h2 u32_h2(unsigned int u) {
    union { unsigned int u; h2 h; } c; c.u = u; return c.h;
}
__device__ __forceinline__ unsigned int h2_u32(h2 h) {
    union { h2 h; unsigned int u; } c; c.h = h; return c.u;
}

template <int CTRL>
__device__ __forceinline__ float dpp_add(float v) {
    int m = __builtin_amdgcn_mov_dpp(__float_as_int(v), CTRL, 0xF, 0xF, true);
    return v + __int_as_float(m);
}

// Dim-parallel: one block per b; lanes 8g..8g+7 cooperate on one output,
// lane owns dims (lane&7)*8..+7. Table f16 [bin][64]: a group's 8 lanes read
// one 128B row -> every ds_read_b128 covers all 32 banks (conflict floor),
// independent of bin randomness. Core is f16 packed math, accumulate via
// v_dot2_f32_f16; 8-lane reduce is 3 DPP adds (VALU pipe only).
__global__ __launch_bounds__(TPB, 8) void scorer_kernel(
    const float* __restrict__ goal,   // (B, 1024, 2)
    const float* __restrict__ ego,    // (B, 4)
    const float* __restrict__ W1,     // (56, 64)
    const float* __restrict__ b1,     // (64)
    const float* __restrict__ W2,     // (64, 1)
    const float* __restrict__ b2,     // (1)
    float* __restrict__ out)          // (B, 1024)
{
    __shared__ uint4 comb[NBIN * 8];   // f16 table: [bin][chunk(8 dims)] = 6.4 KB
    __shared__ uint2 sxy[1024];        // per-output {f16x2(x,y), bin*8} = 8 KB

    const int b    = blockIdx.x;
    const int tid  = threadIdx.x;
    const int lane = tid & 63;
    const int w    = tid >> 6;

    // ---- table build: thread owns f16-pair column (d0,d0+1), d0 = 2*(tid&31)
    const float4 eg = ((const float4*)ego)[b];
    const int   dp = tid & 31;
    const int   d0 = dp * 2, d1 = d0 + 1;
    const float ev0 = b1[d0] + eg.x * W1[52*DIM+d0] + eg.y * W1[53*DIM+d0]
                             + eg.z * W1[54*DIM+d0] + eg.w * W1[55*DIM+d0];
    const float ev1 = b1[d1] + eg.x * W1[52*DIM+d1] + eg.y * W1[53*DIM+d1]
                             + eg.z * W1[54*DIM+d1] + eg.w * W1[55*DIM+d1];
    for (int pi = tid; pi < NBIN * 32; pi += TPB) {
        int bin = pi >> 5;                       // pi&31 == dp for all iters
        float2 wv = ((const float2*)W1)[bin * 32 + dp];
        h2 hv = {(_Float16)(wv.x + ev0), (_Float16)(wv.y + ev1)};   // RNE
        ((unsigned int*)comb)[bin * 32 + dp] = h2_u32(hv);
    }

    // ---- xy/bin staging: this wave's 256 outputs, 64 per round
    const float2* gp = (const float2*)goal + (size_t)b * 1024 + w * 256;
#pragma unroll
    for (int r = 0; r < 4; ++r) {
        float2 pv = gp[r * 64 + lane];
        // exact IEEE f32 replication of jax: floor((sqrt(x*x+y*y)/50)*50), clip
        float r2 = __fadd_rn(__fmul_rn(pv.x, pv.x), __fmul_rn(pv.y, pv.y));
        float fv = floorf(__fmul_rn(__fdiv_rn(__fsqrt_rn(r2), 50.0f), 50.0f));
        int ix = (int)fv;
        ix = ix < 0 ? 0 : (ix > NBIN - 1 ? NBIN - 1 : ix);
        h2 xyh = {(_Float16)pv.x, (_Float16)pv.y};                  // RNE
        sxy[w * 256 + r * 64 + lane] = make_uint2(h2_u32(xyh), (unsigned)(ix * 8));
    }
    __syncthreads();

    // ---- per-lane f16 weights for dims dd..dd+7
    const int dd = (lane & 7) * 8;
    const float4 al = *(const float4*)(W1 + 50 * DIM + dd);
    const float4 ah = *(const float4*)(W1 + 50 * DIM + dd + 4);
    const float4 ul = *(const float4*)(W1 + 51 * DIM + dd);
    const float4 uh = *(const float4*)(W1 + 51 * DIM + dd + 4);
    const float4 cl = *(const float4*)(W2 + dd);
    const float4 ch = *(const float4*)(W2 + dd + 4);
    const h2 wa0 = {(_Float16)al.x, (_Float16)al.y}, wa1 = {(_Float16)al.z, (_Float16)al.w};
    const h2 wa2 = {(_Float16)ah.x, (_Float16)ah.y}, wa3 = {(_Float16)ah.z, (_Float16)ah.w};
    const h2 wu0 = {(_Float16)ul.x, (_Float16)ul.y}, wu1 = {(_Float16)ul.z, (_Float16)ul.w};
    const h2 wu2 = {(_Float16)uh.x, (_Float16)uh.y}, wu3 = {(_Float16)uh.z, (_Float16)uh.w};
    const h2 wc0 = {(_Float16)cl.x, (_Float16)cl.y}, wc1 = {(_Float16)cl.z, (_Float16)cl.w};
    const h2 wc2 = {(_Float16)ch.x, (_Float16)ch.y}, wc3 = {(_Float16)ch.z, (_Float16)ch.w};
    const h2 hz = {(_Float16)0.0f, (_Float16)0.0f};
    const float bias2 = b2[0];

    const int   sel   = lane & 7;               // sub-round this lane keeps
    const int   ebase = w * 256 + (lane >> 3) * 8;
    const uint4* gpt  = comb + (lane & 7);

// t = y*wu + g ; t = x*wa + t ; t = max(t,0) ; acc += dot2(t, wc)
#define PAIR(GW, WA, WU, WC)                                                  \
    {                                                                         \
        h2 gg = u32_h2(GW);                                                   \
        h2 tt;                                                                \
        asm("v_pk_fma_f16 %0, %1, %2, %3 op_sel:[1,0,0] op_sel_hi:[1,1,1]"    \
            : "=v"(tt) : "v"(xy), "v"(WU), "v"(gg));                          \
        asm("v_pk_fma_f16 %0, %1, %2, %0 op_sel:[0,0,0] op_sel_hi:[0,1,1]"    \
            : "+v"(tt) : "v"(xy), "v"(WA));                                   \
        asm("v_pk_max_f16 %0, %0, %1" : "+v"(tt) : "v"(hz));                  \
        acc = __builtin_amdgcn_fdot2(tt, WC, acc, false);                     \
    }

#pragma unroll
    for (int r = 0; r < 4; ++r) {
        float keep = 0.0f;
#pragma unroll
        for (int s = 0; s < 8; ++s) {
            uint2 e  = sxy[ebase + r * 64 + s];       // 8-way broadcast b64
            h2    xy = u32_h2(e.x);
            uint4 gv = gpt[e.y];                      // full-row b128, conflict-free
            float acc = 0.0f;
            PAIR(gv.x, wa0, wu0, wc0);
            PAIR(gv.y, wa1, wu1, wc1);
            PAIR(gv.z, wa2, wu2, wc2);
            PAIR(gv.w, wa3, wu3, wc3);
            acc = dpp_add<0xB1>(acc);    // quad_perm [1,0,3,2]  (xor 1)
            acc = dpp_add<0x4E>(acc);    // quad_perm [2,3,0,1]  (xor 2)
            acc = dpp_add<0x141>(acc);   // row_half_mirror      (xor 4 in octet)
            keep = (s == sel) ? acc : keep;
        }
        out[(size_t)b * 1024 + w * 256 + r * 64 + lane] = keep + bias2;
    }
#undef PAIR
}

extern "C" void kernel_launch(void* const* d_in, const int* in_sizes, int n_in,
                              void* d_out, int out_size, void* d_ws, size_t ws_size,
                              hipStream_t stream) {
    const float* goal = (const float*)d_in[0];
    const float* ego  = (const float*)d_in[1];
    const float* W1   = (const float*)d_in[2];
    const float* b1   = (const float*)d_in[3];
    const float* W2   = (const float*)d_in[4];
    const float* b2   = (const float*)d_in[5];
    float* out = (float*)d_out;

    int B = in_sizes[1] / 4;          // ego_state is (B, 4); K fixed at 1024
    scorer_kernel<<<dim3(B), dim3(TPB), 0, stream>>>(goal, ego, W1, b1, W2, b2, out);
}

// Round 7
// 21.656 us; speedup vs baseline: 1.3806x; 1.0114x over previous
//
#include <hip/hip_runtime.h>

#define NBIN 50
#define DIM  64
#define TPB  256

typedef _Float16 h2 __attribute__((ext_vector_type(2)));

__device__ __forceinline__ h2 u32_h2(unsigned int u) {
    union { unsigned int u; h2 h; } c; c.u = u; return c.h;
}
__device__ __forceinline__ unsigned int h2_u32(h2 h) {
    union { h2 h; unsigned int u; } c; c.h = h; return c.u;
}

template <int CTRL>
__device__ __forceinline__ float xg_dpp(float v) {   // partner-lane value via DPP quad_perm
    return __int_as_float(__builtin_amdgcn_mov_dpp(__float_as_int(v), CTRL, 0xF, 0xF, true));
}
__device__ __forceinline__ float xg_sw4(float v) {   // lane ^ 4 via ds_swizzle xor-BitMode
    return __int_as_float(__builtin_amdgcn_ds_swizzle(__float_as_int(v), 0x101F));
}

// Octet broadcast: every lane reads the value of lane (octet_base | S), S static.
// BitMode offset = xor<<10 | or<<5 | and ; and=0x18 keeps octet bits, or=S.
#define SW_OCT(v, S) __builtin_amdgcn_ds_swizzle((v), (((S) << 5) | 0x18))

// Dim-parallel (R6 structure): lanes 8g..8g+7 cooperate on one output; lane
// owns dims (lane&7)*8..+7. f16 table [bin][64] (128 B rows): a slot's gather
// reads one full row across the octet -> every bank gets exactly 8 dword
// accesses per b128 = conflict floor, independent of bin randomness.
// R7: entries stay in registers (ds_swizzle octet broadcast, no sxy staging);
// 8-slot select-butterfly reduce (28 instr vs 64) leaves output lane&7 in lane.
__global__ __launch_bounds__(TPB, 8) void scorer_kernel(
    const float* __restrict__ goal,   // (B, 1024, 2)
    const float* __restrict__ ego,    // (B, 4)
    const float* __restrict__ W1,     // (56, 64)
    const float* __restrict__ b1,     // (64)
    const float* __restrict__ W2,     // (64, 1)
    const float* __restrict__ b2,     // (1)
    float* __restrict__ out)          // (B, 1024)
{
    __shared__ uint4 comb[NBIN * 8];   // f16 table: [bin][8 chunks of 8 dims] = 6.4 KB

    const int b    = blockIdx.x;
    const int tid  = threadIdx.x;
    const int lane = tid & 63;
    const int w    = tid >> 6;

    // ---- upfront: this lane's 4 entries (rounds r=0..3), exact IEEE bin chain
    const float2* gp = (const float2*)goal + (size_t)b * 1024 + w * 256;
    int xyh[4], bo[4];
#pragma unroll
    for (int r = 0; r < 4; ++r) {
        float2 pv = gp[r * 64 + lane];
        float r2 = __fadd_rn(__fmul_rn(pv.x, pv.x), __fmul_rn(pv.y, pv.y));
        float fv = floorf(__fmul_rn(__fdiv_rn(__fsqrt_rn(r2), 50.0f), 50.0f));
        int ix = (int)fv;
        ix = ix < 0 ? 0 : (ix > NBIN - 1 ? NBIN - 1 : ix);
        bo[r] = ix * 8;                                   // uint4-index of row
        h2 xyp = {(_Float16)pv.x, (_Float16)pv.y};        // RNE
        xyh[r] = (int)h2_u32(xyp);
    }

    // ---- table build: thread owns f16-pair column (d0,d0+1), d0 = 2*(tid&31)
    const float4 eg = ((const float4*)ego)[b];
    const int   dp = tid & 31;
    const int   d0 = dp * 2, d1 = d0 + 1;
    const float ev0 = b1[d0] + eg.x * W1[52*DIM+d0] + eg.y * W1[53*DIM+d0]
                             + eg.z * W1[54*DIM+d0] + eg.w * W1[55*DIM+d0];
    const float ev1 = b1[d1] + eg.x * W1[52*DIM+d1] + eg.y * W1[53*DIM+d1]
                             + eg.z * W1[54*DIM+d1] + eg.w * W1[55*DIM+d1];
    for (int pi = tid; pi < NBIN * 32; pi += TPB) {
        int bin = pi >> 5;                                // pi&31 == dp always
        float2 wv = ((const float2*)W1)[bin * 32 + dp];
        h2 hv = {(_Float16)(wv.x + ev0), (_Float16)(wv.y + ev1)};
        ((unsigned int*)comb)[bin * 32 + dp] = h2_u32(hv);
    }
    __syncthreads();

    // ---- per-lane f16 weights for dims dd..dd+7
    const int dd = (lane & 7) * 8;
    const float4 al = *(const float4*)(W1 + 50 * DIM + dd);
    const float4 ah = *(const float4*)(W1 + 50 * DIM + dd + 4);
    const float4 ul = *(const float4*)(W1 + 51 * DIM + dd);
    const float4 uh = *(const float4*)(W1 + 51 * DIM + dd + 4);
    const float4 cl = *(const float4*)(W2 + dd);
    const float4 ch = *(const float4*)(W2 + dd + 4);
    const h2 wa0 = {(_Float16)al.x, (_Float16)al.y}, wa1 = {(_Float16)al.z, (_Float16)al.w};
    const h2 wa2 = {(_Float16)ah.x, (_Float16)ah.y}, wa3 = {(_Float16)ah.z, (_Float16)ah.w};
    const h2 wu0 = {(_Float16)ul.x, (_Float16)ul.y}, wu1 = {(_Float16)ul.z, (_Float16)ul.w};
    const h2 wu2 = {(_Float16)uh.x, (_Float16)uh.y}, wu3 = {(_Float16)uh.z, (_Float16)uh.w};
    const h2 wc0 = {(_Float16)cl.x, (_Float16)cl.y}, wc1 = {(_Float16)cl.z, (_Float16)cl.w};
    const h2 wc2 = {(_Float16)ch.x, (_Float16)ch.y}, wc3 = {(_Float16)ch.z, (_Float16)ch.w};
    const h2 hz = {(_Float16)0.0f, (_Float16)0.0f};
    const float bias2 = b2[0];

    const uint4* gpt = comb + (lane & 7);
    const bool p1 = (lane & 1) != 0, p2 = (lane & 2) != 0, p4 = (lane & 4) != 0;

// t = y*wu + g ; t = x*wa + t ; t = max(t,0) ; acc += dot2(t, wc)
#define PAIR(GW, WA, WU, WC)                                                  \
    {                                                                         \
        h2 gg = u32_h2(GW);                                                   \
        h2 tt;                                                                \
        asm("v_pk_fma_f16 %0, %1, %2, %3 op_sel:[1,0,0] op_sel_hi:[1,1,1]"    \
            : "=v"(tt) : "v"(xy), "v"(WU), "v"(gg));                          \
        asm("v_pk_fma_f16 %0, %1, %2, %0 op_sel:[0,0,0] op_sel_hi:[0,1,1]"    \
            : "+v"(tt) : "v"(xy), "v"(WA));                                   \
        asm("v_pk_max_f16 %0, %0, %1" : "+v"(tt) : "v"(hz));                  \
        acc = __builtin_amdgcn_fdot2(tt, WC, acc, false);                     \
    }

// slot S of this octet: broadcast entry from lane (octet|S), gather row, core
#define S_ITER(S, ACC)                                                        \
    {                                                                         \
        h2   xy = u32_h2((unsigned)SW_OCT(xyr, S));                           \
        int  bos = SW_OCT(bor, S);                                            \
        uint4 gv = gpt[bos];                                                  \
        float acc = 0.0f;                                                     \
        PAIR(gv.x, wa0, wu0, wc0);                                            \
        PAIR(gv.y, wa1, wu1, wc1);                                            \
        PAIR(gv.z, wa2, wu2, wc2);                                            \
        PAIR(gv.w, wa3, wu3, wc3);                                            \
        ACC = acc;                                                            \
    }

#define ROUND(R)                                                              \
    {                                                                         \
        const int xyr = xyh[R], bor = bo[R];                                  \
        float a0, a1, a2, a3, a4, a5, a6, a7;                                 \
        S_ITER(0, a0) S_ITER(1, a1) S_ITER(2, a2) S_ITER(3, a3)               \
        S_ITER(4, a4) S_ITER(5, a5) S_ITER(6, a6) S_ITER(7, a7)               \
        /* select-butterfly: lane ends with full sum for slot lane&7 */       \
        float q0 = (p1 ? a1 : a0) + xg_dpp<0xB1>(p1 ? a0 : a1);               \
        float q1 = (p1 ? a3 : a2) + xg_dpp<0xB1>(p1 ? a2 : a3);               \
        float q2 = (p1 ? a5 : a4) + xg_dpp<0xB1>(p1 ? a4 : a5);               \
        float q3 = (p1 ? a7 : a6) + xg_dpp<0xB1>(p1 ? a6 : a7);               \
        float r0 = (p2 ? q1 : q0) + xg_dpp<0x4E>(p2 ? q0 : q1);               \
        float r1 = (p2 ? q3 : q2) + xg_dpp<0x4E>(p2 ? q2 : q3);               \
        float vf = (p4 ? r1 : r0) + xg_sw4(p4 ? r0 : r1);                     \
        out[(size_t)b * 1024 + w * 256 + (R) * 64 + lane] = vf + bias2;       \
    }

    ROUND(0)
    ROUND(1)
    ROUND(2)
    ROUND(3)

#undef ROUND
#undef S_ITER
#undef PAIR
}

extern "C" void kernel_launch(void* const* d_in, const int* in_sizes, int n_in,
                              void* d_out, int out_size, void* d_ws, size_t ws_size,
                              hipStream_t stream) {
    const float* goal = (const float*)d_in[0];
    const float* ego  = (const float*)d_in[1];
    const float* W1   = (const float*)d_in[2];
    const float* b1   = (const float*)d_in[3];
    const float* W2   = (const float*)d_in[4];
    const float* b2   = (const float*)d_in[5];
    float* out = (float*)d_out;

    int B = in_sizes[1] / 4;          // ego_state is (B, 4); K fixed at 1024
    scorer_kernel<<<dim3(B), dim3(TPB), 0, stream>>>(goal, ego, W1, b1, W2, b2, out);
}